// Round 2
// baseline (191.816 us; speedup 1.0000x reference)
//
#include <hip/hip_runtime.h>
#include <hip/hip_bf16.h>
#include <math.h>

#define Hn 6
#define Bn 512
#define Dn 2048
#define Cn 1000
#define Cpad 1024
#define TAUv 0.5f
#define KSPLIT 4
#define KPER (Dn / KSPLIT)   // 512 k per kz slice
#define NIT (KPER / 32)      // 16 k-iters per block

typedef unsigned int u32;
typedef unsigned short u16;
typedef __attribute__((ext_vector_type(8))) short short8;
typedef __attribute__((ext_vector_type(4))) float f32x4;

union FragU { u32 d[4]; short8 s; };

// pack two fp32 -> one dword of bf16 (RNE, f0 in low half; lowers to v_cvt_pk_bf16_f32)
__device__ __forceinline__ u32 cvt_pk2(float f0, float f1) {
  union { __hip_bfloat162 h; u32 u; } cv;
  cv.h = __float22bfloat162_rn(make_float2(f0, f1));
  return cv.u;
}

// 8 fp32 -> hi short8 (bf16) + lo short8 (bf16 of residual). RNE both, matching the
// old conv_k bf16_rne exactly -> bit-identical logits vs the 188us version.
__device__ __forceinline__ void pack8f(const float* f, FragU& hi, FragU& lo) {
  float r[8];
#pragma unroll
  for (int i = 0; i < 4; ++i) {
    const u32 d = cvt_pk2(f[2 * i], f[2 * i + 1]);
    hi.d[i] = d;
    r[2 * i]     = f[2 * i]     - __uint_as_float(d << 16);
    r[2 * i + 1] = f[2 * i + 1] - __uint_as_float(d & 0xffff0000u);
  }
#pragma unroll
  for (int i = 0; i < 4; ++i) lo.d[i] = cvt_pk2(r[2 * i], r[2 * i + 1]);
}

// async global->LDS DMA, 16 B/lane; LDS dest = wave-uniform base + lane*16 (linear!)
__device__ __forceinline__ void dma16(const void* g, void* l) {
  __builtin_amdgcn_global_load_lds(
      (const __attribute__((address_space(1))) u32*)g,
      (__attribute__((address_space(3))) u32*)l, 16, 0, 0);
}

// ============ fused convert + split-bf16 MFMA GEMM ============
// Reads fp32 feats/W directly (conversion kernel eliminated). Per k-iter:
//   stage fp32 A[128][32] (XOR-swizzled 16B chunks) + B[32][128] (linear) via DMA,
//   2-phase double-buffer (stage tile it+1 before computing tile it),
//   pack to bf16 hi/lo in regs feeding 3-term split MFMA.
// LDS: 2 x (A 16 KB | B 16 KB) = 64 KB.
// A swizzle (rule #21 both-sides): LDS[r][p] = G[r][p ^ (r&7)], p = 16B chunk idx,
// applied on the per-lane GLOBAL source; DMA dest stays linear; read applies same XOR.
__global__ __launch_bounds__(256, 2) void gemm_k(
    const float* __restrict__ feats, const float* __restrict__ W,
    const float* __restrict__ bias, float* __restrict__ logits,
    float* __restrict__ scalars)
{
  const int h  = blockIdx.z >> 2;
  const int kz = blockIdx.z & 3;
  const int m0 = blockIdx.y * 128;
  const int n0 = blockIdx.x * 128;
  const int t = threadIdx.x, lane = t & 63, w = t >> 6;

  if (t == 0 && blockIdx.x == 0 && blockIdx.y == 0 && blockIdx.z == 0) {
    scalars[0] = 0.f; scalars[1] = 0.f;     // reset accumulators for confpick
  }

  __shared__ __align__(16) float lds[2][8192];   // 2 x (A 4096 f32 | B 4096 f32) = 64 KB

  // ---- per-lane DMA source/dest: waves 0,1 stage A halves; waves 2,3 stage B halves ----
  // each wave: 8 x dma16 per k-iter, each a 1 KB coalesced burst
  const float* gsrc; size_t gci, gadv; int dst0;
  if (w < 2) {
    const int r = w * 64 + (lane >> 3);              // tile row; call i adds 8 rows
    const int q = (lane & 7) ^ ((lane >> 3) & 7);    // pre-swizzled source chunk
    gsrc = feats + ((size_t)(h * Bn + m0 + r)) * Dn + kz * KPER + q * 4;
    gci  = (size_t)8 * Dn;                            // +8 rows per call
    gadv = 32;                                        // +32 k per iter
    dst0 = w * 8192 + lane * 16;
  } else {
    const int kk  = (w - 2) * 16 + (lane >> 5);       // tile k-row; call i adds 2
    const int c4  = n0 + (lane & 31) * 4;
    const int c4c = (c4 + 3 < Cn) ? c4 : (Cn - 4);    // clamp OOB cols (junk cols >=Cn never stored)
    gsrc = W + ((size_t)h * Dn + kz * KPER + kk) * Cn + c4c;
    gci  = (size_t)2 * Cn;                            // +2 k-rows per call
    gadv = (size_t)32 * Cn;                           // +32 k per iter
    dst0 = 16384 + (w - 2) * 8192 + lane * 16;
  }

  const int fl = lane & 15, fq = lane >> 4;
  const int wm = (w & 1) * 64, wn = (w >> 1) * 64;
  const int sxor = fl & 7;                            // == row&7 for all this lane's A rows

  f32x4 acc[4][4];
#pragma unroll
  for (int i = 0; i < 4; ++i)
#pragma unroll
    for (int j = 0; j < 4; ++j) acc[i][j] = (f32x4){0.f, 0.f, 0.f, 0.f};

  // prologue: stage tile 0 into buf 0
  {
    char* sb = (char*)&lds[0][0];
#pragma unroll
    for (int i = 0; i < 8; ++i) dma16(gsrc + i * gci, sb + dst0 + i * 1024);
  }
  __syncthreads();

#define COMPUTE_TILE(IT)                                                              \
  {                                                                                   \
    const char*  ab = (const char*)&lds[(IT) & 1][0];                                 \
    const float* bb = (const float*)(ab + 16384);                                     \
    FragU ah[4], al[4];                                                               \
    _Pragma("unroll")                                                                 \
    for (int mt = 0; mt < 4; ++mt) {                                                  \
      const int r = wm + mt * 16 + fl;                                                \
      const float4 v0 = *(const float4*)(ab + r * 128 + ((((fq * 2)    ) ^ sxor) * 16)); \
      const float4 v1 = *(const float4*)(ab + r * 128 + ((((fq * 2) + 1) ^ sxor) * 16)); \
      float f[8] = {v0.x, v0.y, v0.z, v0.w, v1.x, v1.y, v1.z, v1.w};                  \
      pack8f(f, ah[mt], al[mt]);                                                      \
    }                                                                                 \
    _Pragma("unroll")                                                                 \
    for (int nt = 0; nt < 4; ++nt) {                                                  \
      const int n = wn + nt * 16 + fl;                                                \
      float f[8];                                                                     \
      _Pragma("unroll")                                                               \
      for (int e = 0; e < 8; ++e) f[e] = bb[(fq * 8 + e) * 128 + n];                  \
      FragU bh, bl;                                                                   \
      pack8f(f, bh, bl);                                                              \
      _Pragma("unroll")                                                               \
      for (int mt = 0; mt < 4; ++mt) {                                                \
        acc[mt][nt] = __builtin_amdgcn_mfma_f32_16x16x32_bf16(ah[mt].s, bh.s, acc[mt][nt], 0, 0, 0); \
        acc[mt][nt] = __builtin_amdgcn_mfma_f32_16x16x32_bf16(ah[mt].s, bl.s, acc[mt][nt], 0, 0, 0); \
        acc[mt][nt] = __builtin_amdgcn_mfma_f32_16x16x32_bf16(al[mt].s, bh.s, acc[mt][nt], 0, 0, 0); \
      }                                                                               \
    }                                                                                 \
  }

  // steady state: unconditional prefetch of tile it+1, compute tile it
  for (int it = 0; it < NIT - 1; ++it) {
    char* sb = (char*)&lds[(it + 1) & 1][0];
    const float* g = gsrc + (size_t)(it + 1) * gadv;
#pragma unroll
    for (int i = 0; i < 8; ++i) dma16(g + i * gci, sb + dst0 + i * 1024);
    COMPUTE_TILE(it);
    __syncthreads();   // drains this iter's prefetch DMA + protects buf reuse
  }
  // epilogue iter: no prefetch
  COMPUTE_TILE(NIT - 1);
#undef COMPUTE_TILE

  // ---- partial stores (+bias on kz 0) ----
  float* part = logits + (size_t)kz * ((size_t)Hn * Bn * Cn);
#pragma unroll
  for (int nt = 0; nt < 4; ++nt) {
    const int col = n0 + wn + nt * 16 + fl;
    if (col >= Cn) continue;
    const float bv = (kz == 0) ? bias[(size_t)h * Cn + col] : 0.f;
#pragma unroll
    for (int mt = 0; mt < 4; ++mt) {
      const int rbase = m0 + wm + mt * 16 + fq * 4;
#pragma unroll
      for (int r = 0; r < 4; ++r)
        part[((size_t)h * Bn + rbase + r) * Cn + col] = acc[mt][nt][r] + bv;
    }
  }
}

// ============ fused conf + route + gather + CE: one block per sample ============
__global__ __launch_bounds__(256) void confpick_k(
    const float* __restrict__ logits, const int* __restrict__ y,
    float* __restrict__ out, float* __restrict__ out_exit,
    float* __restrict__ scalars)
{
  const int b = blockIdx.x, tid = threadIdx.x;
  const int lane = tid & 63, w = tid >> 6;
  const size_t S = (size_t)Hn * Bn * Cn;
  __shared__ float ms[Hn], ss[Hn];

  // ---- per-row softmax stats: wave w covers rows w and w+4 ----
  for (int h = w; h < Hn; h += 4) {
    const float* p = logits + ((size_t)h * Bn + b) * Cn;
    float vv[16];
#pragma unroll
    for (int i = 0; i < 4; ++i) {
      const int c4 = i * 256 + lane * 4;
      if (c4 + 3 < Cn) {
        const float4 v0 = *(const float4*)(p + c4);
        const float4 v1 = *(const float4*)(p + S + c4);
        const float4 v2 = *(const float4*)(p + 2 * S + c4);
        const float4 v3 = *(const float4*)(p + 3 * S + c4);
        vv[4 * i + 0] = v0.x + v1.x + v2.x + v3.x;
        vv[4 * i + 1] = v0.y + v1.y + v2.y + v3.y;
        vv[4 * i + 2] = v0.z + v1.z + v2.z + v3.z;
        vv[4 * i + 3] = v0.w + v1.w + v2.w + v3.w;
      } else {
#pragma unroll
        for (int j = 0; j < 4; ++j) {
          const int c = c4 + j;
          vv[4 * i + j] = (c < Cn) ? p[c] + p[S + c] + p[2 * S + c] + p[3 * S + c]
                                   : -3.4e38f;
        }
      }
    }
    float m = -3.4e38f;
#pragma unroll
    for (int i = 0; i < 16; ++i) m = fmaxf(m, vv[i]);
#pragma unroll
    for (int off = 32; off >= 1; off >>= 1) m = fmaxf(m, __shfl_xor(m, off));
    float s = 0.f;
#pragma unroll
    for (int i = 0; i < 16; ++i) s += (vv[i] > -3.0e38f) ? expf(vv[i] - m) : 0.f;
#pragma unroll
    for (int off = 32; off >= 1; off >>= 1) s += __shfl_xor(s, off);
    if (lane == 0) { ms[h] = m; ss[h] = s; }
  }
  __syncthreads();

  // ---- route (uniform across block, from LDS stats) ----
  int first = -1, best = 0;
  float bestc = -3.4e38f;
#pragma unroll
  for (int h = 0; h < Hn; ++h) {
    const float c = 1.0f / ss[h];                   // max softmax prob
    if (first < 0 && c >= TAUv) first = h;
    if (c > bestc) { bestc = c; best = h; }         // strict > keeps first occurrence
  }
  const int ex = (first >= 0) ? first : best;
  const float* p = logits + ((size_t)ex * Bn + b) * Cn;

  // ---- gather chosen row (L2-warm re-read), argmax, store ----
  const int c4 = tid * 4;
  float vv[4] = {-3.4e38f, -3.4e38f, -3.4e38f, -3.4e38f};
  if (c4 + 3 < Cn) {
    const float4 v0 = *(const float4*)(p + c4);
    const float4 v1 = *(const float4*)(p + S + c4);
    const float4 v2 = *(const float4*)(p + 2 * S + c4);
    const float4 v3 = *(const float4*)(p + 3 * S + c4);
    vv[0] = v0.x + v1.x + v2.x + v3.x;
    vv[1] = v0.y + v1.y + v2.y + v3.y;
    vv[2] = v0.z + v1.z + v2.z + v3.z;
    vv[3] = v0.w + v1.w + v2.w + v3.w;
  }
  float vm = -3.4e38f; int im = 1 << 30;
#pragma unroll
  for (int j = 0; j < 4; ++j) {
    const int c = c4 + j;
    if (c < Cn) {
      out[(size_t)b * Cn + c] = vv[j];
      if (vv[j] > vm) { vm = vv[j]; im = c; }       // ascending c keeps first max
    }
  }
#pragma unroll
  for (int off = 32; off >= 1; off >>= 1) {
    const float ov = __shfl_xor(vm, off);
    const int   oi = __shfl_xor(im, off);
    if (ov > vm || (ov == vm && oi < im)) { vm = ov; im = oi; }
  }
  __shared__ float rm[4]; __shared__ int ri[4];
  if (lane == 0) { rm[w] = vm; ri[w] = im; }
  __syncthreads();
  if (tid == 0) {
    float bm = rm[0]; int bi = ri[0];
    for (int q = 1; q < 4; ++q)
      if (rm[q] > bm || (rm[q] == bm && ri[q] < bi)) { bm = rm[q]; bi = ri[q]; }
    const int yt = y[b];
    const float ryt = p[yt] + p[S + yt] + p[2 * S + yt] + p[3 * S + yt];
    const float lp = ryt - ms[ex] - logf(ss[ex]);
    out_exit[b] = (float)ex;
    atomicAdd(&scalars[0], -lp * (1.0f / (float)Bn));
    atomicAdd(&scalars[1], ((bi == yt) ? 1.f : 0.f) * (1.0f / (float)Bn));
  }
}

extern "C" void kernel_launch(void* const* d_in, const int* in_sizes, int n_in,
                              void* d_out, int out_size, void* d_ws, size_t ws_size,
                              hipStream_t stream) {
  const float* feats = (const float*)d_in[0];   // [H,B,D] fp32
  const float* W     = (const float*)d_in[1];   // [H,D,C] fp32
  const float* bias  = (const float*)d_in[2];   // [H,C]
  const int*   y     = (const int*)d_in[3];     // [B]
  float* out = (float*)d_out;                   // [B*C | B | 1 | 1]

  // ws: logits partials only: KSPLIT * H*B*C f32 = 49,152,000 B
  float* logits = (float*)d_ws;
  float* out_exit    = out + (size_t)Bn * Cn;
  float* out_scalars = out + (size_t)Bn * Cn + Bn;

  gemm_k<<<dim3(Cpad / 128, Bn / 128, Hn * KSPLIT), 256, 0, stream>>>(
      feats, W, bias, logits, out_scalars);
  confpick_k<<<Bn, 256, 0, stream>>>(logits, y, out, out_exit, out_scalars);
}

// Round 3
// 188.876 us; speedup vs baseline: 1.0156x; 1.0156x over previous
//
#include <hip/hip_runtime.h>
#include <hip/hip_bf16.h>
#include <math.h>

#define Hn 6
#define Bn 512
#define Dn 2048
#define Cn 1000
#define Cpad 1024
#define TAUv 0.5f
#define KSPLIT 4
#define KPER (Dn / KSPLIT)   // 512 k per kz slice
#define NIT (KPER / 32)      // 16 k-iters per block

typedef unsigned int u32;
typedef unsigned short u16;
typedef __attribute__((ext_vector_type(8))) short short8;
typedef __attribute__((ext_vector_type(4))) float f32x4;

union FragU { u32 d[4]; short8 s; };

// pack two fp32 -> one dword of bf16 (RNE, f0 in low half; lowers to v_cvt_pk_bf16_f32)
__device__ __forceinline__ u32 cvt_pk2(float f0, float f1) {
  union { __hip_bfloat162 h; u32 u; } cv;
  cv.h = __float22bfloat162_rn(make_float2(f0, f1));
  return cv.u;
}

// 8 fp32 -> hi short8 (bf16) + lo short8 (bf16 of residual). RNE both -> bit-identical
// to the verified 0.03125-absmax pipeline.
__device__ __forceinline__ void pack8f(const float* f, FragU& hi, FragU& lo) {
  float r[8];
#pragma unroll
  for (int i = 0; i < 4; ++i) {
    const u32 d = cvt_pk2(f[2 * i], f[2 * i + 1]);
    hi.d[i] = d;
    r[2 * i]     = f[2 * i]     - __uint_as_float(d << 16);
    r[2 * i + 1] = f[2 * i + 1] - __uint_as_float(d & 0xffff0000u);
  }
#pragma unroll
  for (int i = 0; i < 4; ++i) lo.d[i] = cvt_pk2(r[2 * i], r[2 * i + 1]);
}

// async global->LDS DMA, 16 B/lane; LDS dest = wave-uniform base + lane*16 (linear!)
__device__ __forceinline__ void dma16(const void* g, void* l) {
  __builtin_amdgcn_global_load_lds(
      (const __attribute__((address_space(1))) u32*)g,
      (__attribute__((address_space(3))) u32*)l, 16, 0, 0);
}

// ============ fused convert + split-bf16 MFMA GEMM ============
// T4 pipeline: per iter {issue next-tile DMA; s_waitcnt vmcnt(8) [current tile landed,
// next tile's 8 loads stay in flight]; raw s_barrier; compute; lgkmcnt(0); raw s_barrier}.
// Swizzles (rule #21 both-sides, source-side pre-swizzle + read-side XOR, dest linear):
//   A: LDS[r][p] = G[r][p ^ (r&7)]          (p = 16B chunk in 128B row)
//   B: LDS[k][p] = G[k][p ^ ((k>>3)<<2)]    (p = 16B chunk in 512B row)
// B read bank math: bank = (chunk*4 + n&3) mod 32; XOR by fq<<2 makes fq{0,2}/{1,3}
// use disjoint bank halves -> <=2-way (free).
__global__ __launch_bounds__(256, 2) void gemm_k(
    const float* __restrict__ feats, const float* __restrict__ W,
    const float* __restrict__ bias, float* __restrict__ logits,
    float* __restrict__ scalars)
{
  const int h  = blockIdx.z >> 2;
  const int kz = blockIdx.z & 3;
  const int m0 = blockIdx.y * 128;
  const int n0 = blockIdx.x * 128;
  const int t = threadIdx.x, lane = t & 63, w = t >> 6;

  if (t == 0 && blockIdx.x == 0 && blockIdx.y == 0 && blockIdx.z == 0) {
    scalars[0] = 0.f; scalars[1] = 0.f;     // reset accumulators for confpick
  }

  __shared__ __align__(16) float lds[2][8192];   // 2 x (A 16 KB | B 16 KB) = 64 KB

  // ---- staging addresses: waves 0,1 stage A halves; waves 2,3 stage B halves ----
  // A: per-lane row r (swizzle r&7 constant across calls -> precomputed source)
  const int rA = (w & 1) * 64 + (lane >> 3);
  const int qA = (lane & 7) ^ ((lane >> 3) & 7);
  const float* gsrcA = feats + ((size_t)(h * Bn + m0 + rA)) * Dn + kz * KPER + qA * 4;
  const size_t gciA = (size_t)8 * Dn;
  const int dstA = w * 8192 + lane * 16;
  // B: swizzle depends on k-row octet -> per-call source computed in STAGE
  const int kb = (w - 2) * 16 + (lane >> 5);
  const int pB = lane & 31;
  const float* Wrow = W + ((size_t)h * Dn + kz * KPER) * Cn;
  const int dstB = 16384 + (w - 2) * 8192 + lane * 16;

  const int fl = lane & 15, fq = lane >> 4;
  const int wm = (w & 1) * 64, wn = (w >> 1) * 64;
  const int sxor = fl & 7;

  f32x4 acc[4][4];
#pragma unroll
  for (int i = 0; i < 4; ++i)
#pragma unroll
    for (int j = 0; j < 4; ++j) acc[i][j] = (f32x4){0.f, 0.f, 0.f, 0.f};

#define STAGE(TILE)                                                                   \
  {                                                                                   \
    char* sb = (char*)&lds[(TILE) & 1][0];                                            \
    if (w < 2) {                                                                      \
      const float* g = gsrcA + (size_t)(TILE) * 32;                                   \
      _Pragma("unroll")                                                               \
      for (int i = 0; i < 8; ++i) dma16(g + i * gciA, sb + dstA + i * 1024);          \
    } else {                                                                          \
      const size_t kt0 = (size_t)(TILE) * 32;                                         \
      _Pragma("unroll")                                                               \
      for (int i = 0; i < 8; ++i) {                                                   \
        const int kl = kb + 2 * i;                                                    \
        const int pc = pB ^ (((kl >> 3) & 3) << 2);                                   \
        int col = n0 + pc * 4;                                                        \
        col = (col + 3 < Cn) ? col : (Cn - 4);                                        \
        dma16(Wrow + (kt0 + kl) * Cn + col, sb + dstB + i * 1024);                    \
      }                                                                               \
    }                                                                                 \
  }

#define COMPUTE_TILE(IT)                                                              \
  {                                                                                   \
    const char*  ab = (const char*)&lds[(IT) & 1][0];                                 \
    const float* bb = (const float*)(ab + 16384);                                     \
    FragU ah[4], al[4];                                                               \
    _Pragma("unroll")                                                                 \
    for (int mt = 0; mt < 4; ++mt) {                                                  \
      const int r = wm + mt * 16 + fl;                                                \
      const float4 v0 = *(const float4*)(ab + r * 128 + ((((fq * 2)    ) ^ sxor) * 16)); \
      const float4 v1 = *(const float4*)(ab + r * 128 + ((((fq * 2) + 1) ^ sxor) * 16)); \
      float f[8] = {v0.x, v0.y, v0.z, v0.w, v1.x, v1.y, v1.z, v1.w};                  \
      pack8f(f, ah[mt], al[mt]);                                                      \
    }                                                                                 \
    _Pragma("unroll")                                                                 \
    for (int nt = 0; nt < 4; ++nt) {                                                  \
      const int n = wn + nt * 16 + fl;                                                \
      const int nsw = ((((n >> 2) ^ (fq << 2)) << 2) | (n & 3));                      \
      float f[8];                                                                     \
      _Pragma("unroll")                                                               \
      for (int e = 0; e < 8; ++e) f[e] = bb[(fq * 8 + e) * 128 + nsw];                \
      FragU bh, bl;                                                                   \
      pack8f(f, bh, bl);                                                              \
      _Pragma("unroll")                                                               \
      for (int mt = 0; mt < 4; ++mt) {                                                \
        acc[mt][nt] = __builtin_amdgcn_mfma_f32_16x16x32_bf16(ah[mt].s, bh.s, acc[mt][nt], 0, 0, 0); \
        acc[mt][nt] = __builtin_amdgcn_mfma_f32_16x16x32_bf16(ah[mt].s, bl.s, acc[mt][nt], 0, 0, 0); \
        acc[mt][nt] = __builtin_amdgcn_mfma_f32_16x16x32_bf16(al[mt].s, bh.s, acc[mt][nt], 0, 0, 0); \
      }                                                                               \
    }                                                                                 \
  }

  // prologue: stage tile 0
  STAGE(0);

  // steady state: T4 counted-vmcnt pipeline (next tile's DMAs fly across compute)
  for (int it = 0; it < NIT - 1; ++it) {
    STAGE(it + 1);                                      // 8 loads/wave -> buf (it+1)&1
    asm volatile("s_waitcnt vmcnt(8)" ::: "memory");    // tile it landed; it+1 in flight
    __builtin_amdgcn_s_barrier();
    __builtin_amdgcn_sched_barrier(0);
    COMPUTE_TILE(it);
    __builtin_amdgcn_sched_barrier(0);
    asm volatile("s_waitcnt lgkmcnt(0)" ::: "memory");  // all LDS reads of buf it&1 done
    __builtin_amdgcn_s_barrier();                       // safe to overwrite buf it&1 next iter
  }
  // epilogue iter: drain last tile's DMA fully
  asm volatile("s_waitcnt vmcnt(0)" ::: "memory");
  __builtin_amdgcn_s_barrier();
  __builtin_amdgcn_sched_barrier(0);
  COMPUTE_TILE(NIT - 1);
#undef COMPUTE_TILE
#undef STAGE

  // ---- partial stores (+bias on kz 0) ----
  float* part = logits + (size_t)kz * ((size_t)Hn * Bn * Cn);
#pragma unroll
  for (int nt = 0; nt < 4; ++nt) {
    const int col = n0 + wn + nt * 16 + fl;
    if (col >= Cn) continue;
    const float bv = (kz == 0) ? bias[(size_t)h * Cn + col] : 0.f;
#pragma unroll
    for (int mt = 0; mt < 4; ++mt) {
      const int rbase = m0 + wm + mt * 16 + fq * 4;
#pragma unroll
      for (int r = 0; r < 4; ++r)
        part[((size_t)h * Bn + rbase + r) * Cn + col] = acc[mt][nt][r] + bv;
    }
  }
}

// ============ fused conf + route + gather + CE: one block per sample ============
__global__ __launch_bounds__(256) void confpick_k(
    const float* __restrict__ logits, const int* __restrict__ y,
    float* __restrict__ out, float* __restrict__ out_exit,
    float* __restrict__ scalars)
{
  const int b = blockIdx.x, tid = threadIdx.x;
  const int lane = tid & 63, w = tid >> 6;
  const size_t S = (size_t)Hn * Bn * Cn;
  __shared__ float ms[Hn], ss[Hn];

  // ---- per-row softmax stats: wave w covers rows w and w+4 ----
  for (int h = w; h < Hn; h += 4) {
    const float* p = logits + ((size_t)h * Bn + b) * Cn;
    float vv[16];
#pragma unroll
    for (int i = 0; i < 4; ++i) {
      const int c4 = i * 256 + lane * 4;
      if (c4 + 3 < Cn) {
        const float4 v0 = *(const float4*)(p + c4);
        const float4 v1 = *(const float4*)(p + S + c4);
        const float4 v2 = *(const float4*)(p + 2 * S + c4);
        const float4 v3 = *(const float4*)(p + 3 * S + c4);
        vv[4 * i + 0] = v0.x + v1.x + v2.x + v3.x;
        vv[4 * i + 1] = v0.y + v1.y + v2.y + v3.y;
        vv[4 * i + 2] = v0.z + v1.z + v2.z + v3.z;
        vv[4 * i + 3] = v0.w + v1.w + v2.w + v3.w;
      } else {
#pragma unroll
        for (int j = 0; j < 4; ++j) {
          const int c = c4 + j;
          vv[4 * i + j] = (c < Cn) ? p[c] + p[S + c] + p[2 * S + c] + p[3 * S + c]
                                   : -3.4e38f;
        }
      }
    }
    float m = -3.4e38f;
#pragma unroll
    for (int i = 0; i < 16; ++i) m = fmaxf(m, vv[i]);
#pragma unroll
    for (int off = 32; off >= 1; off >>= 1) m = fmaxf(m, __shfl_xor(m, off));
    float s = 0.f;
#pragma unroll
    for (int i = 0; i < 16; ++i) s += (vv[i] > -3.0e38f) ? expf(vv[i] - m) : 0.f;
#pragma unroll
    for (int off = 32; off >= 1; off >>= 1) s += __shfl_xor(s, off);
    if (lane == 0) { ms[h] = m; ss[h] = s; }
  }
  __syncthreads();

  // ---- route (uniform across block, from LDS stats) ----
  int first = -1, best = 0;
  float bestc = -3.4e38f;
#pragma unroll
  for (int h = 0; h < Hn; ++h) {
    const float c = 1.0f / ss[h];                   // max softmax prob
    if (first < 0 && c >= TAUv) first = h;
    if (c > bestc) { bestc = c; best = h; }         // strict > keeps first occurrence
  }
  const int ex = (first >= 0) ? first : best;
  const float* p = logits + ((size_t)ex * Bn + b) * Cn;

  // ---- gather chosen row (L2-warm re-read), argmax, store ----
  const int c4 = tid * 4;
  float vv[4] = {-3.4e38f, -3.4e38f, -3.4e38f, -3.4e38f};
  if (c4 + 3 < Cn) {
    const float4 v0 = *(const float4*)(p + c4);
    const float4 v1 = *(const float4*)(p + S + c4);
    const float4 v2 = *(const float4*)(p + 2 * S + c4);
    const float4 v3 = *(const float4*)(p + 3 * S + c4);
    vv[0] = v0.x + v1.x + v2.x + v3.x;
    vv[1] = v0.y + v1.y + v2.y + v3.y;
    vv[2] = v0.z + v1.z + v2.z + v3.z;
    vv[3] = v0.w + v1.w + v2.w + v3.w;
  }
  float vm = -3.4e38f; int im = 1 << 30;
#pragma unroll
  for (int j = 0; j < 4; ++j) {
    const int c = c4 + j;
    if (c < Cn) {
      out[(size_t)b * Cn + c] = vv[j];
      if (vv[j] > vm) { vm = vv[j]; im = c; }       // ascending c keeps first max
    }
  }
#pragma unroll
  for (int off = 32; off >= 1; off >>= 1) {
    const float ov = __shfl_xor(vm, off);
    const int   oi = __shfl_xor(im, off);
    if (ov > vm || (ov == vm && oi < im)) { vm = ov; im = oi; }
  }
  __shared__ float rm[4]; __shared__ int ri[4];
  if (lane == 0) { rm[w] = vm; ri[w] = im; }
  __syncthreads();
  if (tid == 0) {
    float bm = rm[0]; int bi = ri[0];
    for (int q = 1; q < 4; ++q)
      if (rm[q] > bm || (rm[q] == bm && ri[q] < bi)) { bm = rm[q]; bi = ri[q]; }
    const int yt = y[b];
    const float ryt = p[yt] + p[S + yt] + p[2 * S + yt] + p[3 * S + yt];
    const float lp = ryt - ms[ex] - logf(ss[ex]);
    out_exit[b] = (float)ex;
    atomicAdd(&scalars[0], -lp * (1.0f / (float)Bn));
    atomicAdd(&scalars[1], ((bi == yt) ? 1.f : 0.f) * (1.0f / (float)Bn));
  }
}

extern "C" void kernel_launch(void* const* d_in, const int* in_sizes, int n_in,
                              void* d_out, int out_size, void* d_ws, size_t ws_size,
                              hipStream_t stream) {
  const float* feats = (const float*)d_in[0];   // [H,B,D] fp32
  const float* W     = (const float*)d_in[1];   // [H,D,C] fp32
  const float* bias  = (const float*)d_in[2];   // [H,C]
  const int*   y     = (const int*)d_in[3];     // [B]
  float* out = (float*)d_out;                   // [B*C | B | 1 | 1]

  // ws: logits partials only: KSPLIT * H*B*C f32 = 49,152,000 B
  float* logits = (float*)d_ws;
  float* out_exit    = out + (size_t)Bn * Cn;
  float* out_scalars = out + (size_t)Bn * Cn + Bn;

  gemm_k<<<dim3(Cpad / 128, Bn / 128, Hn * KSPLIT), 256, 0, stream>>>(
      feats, W, bias, logits, out_scalars);
  confpick_k<<<Bn, 256, 0, stream>>>(logits, y, out, out_exit, out_scalars);
}

// Round 4
// 179.145 us; speedup vs baseline: 1.0707x; 1.0543x over previous
//
#include <hip/hip_runtime.h>
#include <hip/hip_bf16.h>
#include <math.h>

#define Hn 6
#define Bn 512
#define Dn 2048
#define Cn 1000
#define Cpad 1024
#define TAUv 0.5f
#define KSPLIT 4
#define KPER (Dn / KSPLIT)   // 512 k per kz slice
#define NIT (KPER / 32)      // 16 k-iters per block

typedef unsigned int u32;
typedef unsigned short u16;
typedef __attribute__((ext_vector_type(8))) short short8;
typedef __attribute__((ext_vector_type(4))) float f32x4;

union FragU { u32 d[4]; short8 s; };

// pack two fp32 -> one dword of bf16 (RNE, f0 in low half; lowers to v_cvt_pk_bf16_f32)
__device__ __forceinline__ u32 cvt_pk2(float f0, float f1) {
  union { __hip_bfloat162 h; u32 u; } cv;
  cv.h = __float22bfloat162_rn(make_float2(f0, f1));
  return cv.u;
}

// 8 fp32 -> hi short8 (bf16) + lo short8 (bf16 of residual). RNE both -> bit-identical
// to the verified 0.03125-absmax pipeline.
__device__ __forceinline__ void pack8f(const float* f, FragU& hi, FragU& lo) {
  float r[8];
#pragma unroll
  for (int i = 0; i < 4; ++i) {
    const u32 d = cvt_pk2(f[2 * i], f[2 * i + 1]);
    hi.d[i] = d;
    r[2 * i]     = f[2 * i]     - __uint_as_float(d << 16);
    r[2 * i + 1] = f[2 * i + 1] - __uint_as_float(d & 0xffff0000u);
  }
#pragma unroll
  for (int i = 0; i < 4; ++i) lo.d[i] = cvt_pk2(r[2 * i], r[2 * i + 1]);
}

// async global->LDS DMA, 16 B/lane; LDS dest = wave-uniform base + lane*16 (linear!)
__device__ __forceinline__ void dma16(const void* g, void* l) {
  __builtin_amdgcn_global_load_lds(
      (const __attribute__((address_space(1))) u32*)g,
      (__attribute__((address_space(3))) u32*)l, 16, 0, 0);
}

// ============ fused convert + split-bf16 MFMA GEMM (unchanged from R3: 88.5us) ============
__global__ __launch_bounds__(256, 2) void gemm_k(
    const float* __restrict__ feats, const float* __restrict__ W,
    const float* __restrict__ bias, float* __restrict__ logits)
{
  const int h  = blockIdx.z >> 2;
  const int kz = blockIdx.z & 3;
  const int m0 = blockIdx.y * 128;
  const int n0 = blockIdx.x * 128;
  const int t = threadIdx.x, lane = t & 63, w = t >> 6;

  __shared__ __align__(16) float lds[2][8192];   // 2 x (A 16 KB | B 16 KB) = 64 KB

  // ---- staging addresses: waves 0,1 stage A halves; waves 2,3 stage B halves ----
  const int rA = (w & 1) * 64 + (lane >> 3);
  const int qA = (lane & 7) ^ ((lane >> 3) & 7);
  const float* gsrcA = feats + ((size_t)(h * Bn + m0 + rA)) * Dn + kz * KPER + qA * 4;
  const size_t gciA = (size_t)8 * Dn;
  const int dstA = w * 8192 + lane * 16;
  const int kb = (w - 2) * 16 + (lane >> 5);
  const int pB = lane & 31;
  const float* Wrow = W + ((size_t)h * Dn + kz * KPER) * Cn;
  const int dstB = 16384 + (w - 2) * 8192 + lane * 16;

  const int fl = lane & 15, fq = lane >> 4;
  const int wm = (w & 1) * 64, wn = (w >> 1) * 64;
  const int sxor = fl & 7;

  f32x4 acc[4][4];
#pragma unroll
  for (int i = 0; i < 4; ++i)
#pragma unroll
    for (int j = 0; j < 4; ++j) acc[i][j] = (f32x4){0.f, 0.f, 0.f, 0.f};

#define STAGE(TILE)                                                                   \
  {                                                                                   \
    char* sb = (char*)&lds[(TILE) & 1][0];                                            \
    if (w < 2) {                                                                      \
      const float* g = gsrcA + (size_t)(TILE) * 32;                                   \
      _Pragma("unroll")                                                               \
      for (int i = 0; i < 8; ++i) dma16(g + i * gciA, sb + dstA + i * 1024);          \
    } else {                                                                          \
      const size_t kt0 = (size_t)(TILE) * 32;                                         \
      _Pragma("unroll")                                                               \
      for (int i = 0; i < 8; ++i) {                                                   \
        const int kl = kb + 2 * i;                                                    \
        const int pc = pB ^ (((kl >> 3) & 3) << 2);                                   \
        int col = n0 + pc * 4;                                                        \
        col = (col + 3 < Cn) ? col : (Cn - 4);                                        \
        dma16(Wrow + (kt0 + kl) * Cn + col, sb + dstB + i * 1024);                    \
      }                                                                               \
    }                                                                                 \
  }

#define COMPUTE_TILE(IT)                                                              \
  {                                                                                   \
    const char*  ab = (const char*)&lds[(IT) & 1][0];                                 \
    const float* bb = (const float*)(ab + 16384);                                     \
    FragU ah[4], al[4];                                                               \
    _Pragma("unroll")                                                                 \
    for (int mt = 0; mt < 4; ++mt) {                                                  \
      const int r = wm + mt * 16 + fl;                                                \
      const float4 v0 = *(const float4*)(ab + r * 128 + ((((fq * 2)    ) ^ sxor) * 16)); \
      const float4 v1 = *(const float4*)(ab + r * 128 + ((((fq * 2) + 1) ^ sxor) * 16)); \
      float f[8] = {v0.x, v0.y, v0.z, v0.w, v1.x, v1.y, v1.z, v1.w};                  \
      pack8f(f, ah[mt], al[mt]);                                                      \
    }                                                                                 \
    _Pragma("unroll")                                                                 \
    for (int nt = 0; nt < 4; ++nt) {                                                  \
      const int n = wn + nt * 16 + fl;                                                \
      const int nsw = ((((n >> 2) ^ (fq << 2)) << 2) | (n & 3));                      \
      float f[8];                                                                     \
      _Pragma("unroll")                                                               \
      for (int e = 0; e < 8; ++e) f[e] = bb[(fq * 8 + e) * 128 + nsw];                \
      FragU bh, bl;                                                                   \
      pack8f(f, bh, bl);                                                              \
      _Pragma("unroll")                                                               \
      for (int mt = 0; mt < 4; ++mt) {                                                \
        acc[mt][nt] = __builtin_amdgcn_mfma_f32_16x16x32_bf16(ah[mt].s, bh.s, acc[mt][nt], 0, 0, 0); \
        acc[mt][nt] = __builtin_amdgcn_mfma_f32_16x16x32_bf16(ah[mt].s, bl.s, acc[mt][nt], 0, 0, 0); \
        acc[mt][nt] = __builtin_amdgcn_mfma_f32_16x16x32_bf16(al[mt].s, bh.s, acc[mt][nt], 0, 0, 0); \
      }                                                                               \
    }                                                                                 \
  }

  STAGE(0);

  for (int it = 0; it < NIT - 1; ++it) {
    STAGE(it + 1);                                      // 8 loads/wave -> buf (it+1)&1
    asm volatile("s_waitcnt vmcnt(8)" ::: "memory");    // tile it landed; it+1 in flight
    __builtin_amdgcn_s_barrier();
    __builtin_amdgcn_sched_barrier(0);
    COMPUTE_TILE(it);
    __builtin_amdgcn_sched_barrier(0);
    asm volatile("s_waitcnt lgkmcnt(0)" ::: "memory");
    __builtin_amdgcn_s_barrier();
  }
  asm volatile("s_waitcnt vmcnt(0)" ::: "memory");
  __builtin_amdgcn_s_barrier();
  __builtin_amdgcn_sched_barrier(0);
  COMPUTE_TILE(NIT - 1);
#undef COMPUTE_TILE
#undef STAGE

  float* part = logits + (size_t)kz * ((size_t)Hn * Bn * Cn);
#pragma unroll
  for (int nt = 0; nt < 4; ++nt) {
    const int col = n0 + wn + nt * 16 + fl;
    if (col >= Cn) continue;
    const float bv = (kz == 0) ? bias[(size_t)h * Cn + col] : 0.f;
#pragma unroll
    for (int mt = 0; mt < 4; ++mt) {
      const int rbase = m0 + wm + mt * 16 + fq * 4;
#pragma unroll
      for (int r = 0; r < 4; ++r)
        part[((size_t)h * Bn + rbase + r) * Cn + col] = acc[mt][nt][r] + bv;
    }
  }
}

// ============ fused conf + route + gather + CE: one block per sample ============
// Atomics removed: per-sample loss/correct written to ws; reduce_k does the mean.
__global__ __launch_bounds__(256) void confpick_k(
    const float* __restrict__ logits, const int* __restrict__ y,
    float* __restrict__ out, float* __restrict__ out_exit,
    float* __restrict__ loss_b, float* __restrict__ corr_b)
{
  const int b = blockIdx.x, tid = threadIdx.x;
  const int lane = tid & 63, w = tid >> 6;
  const size_t S = (size_t)Hn * Bn * Cn;
  __shared__ float ms[Hn], ss[Hn];

  // ---- per-row softmax stats: wave w covers rows w and w+4 ----
  for (int h = w; h < Hn; h += 4) {
    const float* p = logits + ((size_t)h * Bn + b) * Cn;
    float vv[16];
#pragma unroll
    for (int i = 0; i < 4; ++i) {
      const int c4 = i * 256 + lane * 4;
      if (c4 + 3 < Cn) {
        const float4 v0 = *(const float4*)(p + c4);
        const float4 v1 = *(const float4*)(p + S + c4);
        const float4 v2 = *(const float4*)(p + 2 * S + c4);
        const float4 v3 = *(const float4*)(p + 3 * S + c4);
        vv[4 * i + 0] = v0.x + v1.x + v2.x + v3.x;
        vv[4 * i + 1] = v0.y + v1.y + v2.y + v3.y;
        vv[4 * i + 2] = v0.z + v1.z + v2.z + v3.z;
        vv[4 * i + 3] = v0.w + v1.w + v2.w + v3.w;
      } else {
#pragma unroll
        for (int j = 0; j < 4; ++j) {
          const int c = c4 + j;
          vv[4 * i + j] = (c < Cn) ? p[c] + p[S + c] + p[2 * S + c] + p[3 * S + c]
                                   : -3.4e38f;
        }
      }
    }
    float m = -3.4e38f;
#pragma unroll
    for (int i = 0; i < 16; ++i) m = fmaxf(m, vv[i]);
#pragma unroll
    for (int off = 32; off >= 1; off >>= 1) m = fmaxf(m, __shfl_xor(m, off));
    float s = 0.f;
#pragma unroll
    for (int i = 0; i < 16; ++i) s += (vv[i] > -3.0e38f) ? expf(vv[i] - m) : 0.f;
#pragma unroll
    for (int off = 32; off >= 1; off >>= 1) s += __shfl_xor(s, off);
    if (lane == 0) { ms[h] = m; ss[h] = s; }
  }
  __syncthreads();

  // ---- route (uniform across block, from LDS stats) ----
  int first = -1, best = 0;
  float bestc = -3.4e38f;
#pragma unroll
  for (int h = 0; h < Hn; ++h) {
    const float c = 1.0f / ss[h];                   // max softmax prob
    if (first < 0 && c >= TAUv) first = h;
    if (c > bestc) { bestc = c; best = h; }         // strict > keeps first occurrence
  }
  const int ex = (first >= 0) ? first : best;
  const float* p = logits + ((size_t)ex * Bn + b) * Cn;

  // ---- gather chosen row (L2-warm re-read), argmax, store ----
  const int c4 = tid * 4;
  float vv[4] = {-3.4e38f, -3.4e38f, -3.4e38f, -3.4e38f};
  if (c4 + 3 < Cn) {
    const float4 v0 = *(const float4*)(p + c4);
    const float4 v1 = *(const float4*)(p + S + c4);
    const float4 v2 = *(const float4*)(p + 2 * S + c4);
    const float4 v3 = *(const float4*)(p + 3 * S + c4);
    vv[0] = v0.x + v1.x + v2.x + v3.x;
    vv[1] = v0.y + v1.y + v2.y + v3.y;
    vv[2] = v0.z + v1.z + v2.z + v3.z;
    vv[3] = v0.w + v1.w + v2.w + v3.w;
  }
  float vm = -3.4e38f; int im = 1 << 30;
#pragma unroll
  for (int j = 0; j < 4; ++j) {
    const int c = c4 + j;
    if (c < Cn) {
      out[(size_t)b * Cn + c] = vv[j];
      if (vv[j] > vm) { vm = vv[j]; im = c; }       // ascending c keeps first max
    }
  }
#pragma unroll
  for (int off = 32; off >= 1; off >>= 1) {
    const float ov = __shfl_xor(vm, off);
    const int   oi = __shfl_xor(im, off);
    if (ov > vm || (ov == vm && oi < im)) { vm = ov; im = oi; }
  }
  __shared__ float rm[4]; __shared__ int ri[4];
  if (lane == 0) { rm[w] = vm; ri[w] = im; }
  __syncthreads();
  if (tid == 0) {
    float bm = rm[0]; int bi = ri[0];
    for (int q = 1; q < 4; ++q)
      if (rm[q] > bm || (rm[q] == bm && ri[q] < bi)) { bm = rm[q]; bi = ri[q]; }
    const int yt = y[b];
    const float ryt = p[yt] + p[S + yt] + p[2 * S + yt] + p[3 * S + yt];
    const float lp = ryt - ms[ex] - logf(ss[ex]);
    out_exit[b] = (float)ex;
    loss_b[b] = -lp;                                 // no atomics: per-sample stash
    corr_b[b] = (bi == yt) ? 1.f : 0.f;
  }
}

// ============ deterministic 1-block mean reduce: 512 -> 2 scalars ============
__global__ __launch_bounds__(256) void reduce_k(
    const float* __restrict__ loss_b, const float* __restrict__ corr_b,
    float* __restrict__ scalars)
{
  const int t = threadIdx.x, lane = t & 63, w = t >> 6;
  float l = loss_b[t] + loss_b[t + 256];
  float c = corr_b[t] + corr_b[t + 256];
#pragma unroll
  for (int off = 32; off >= 1; off >>= 1) {
    l += __shfl_xor(l, off);
    c += __shfl_xor(c, off);
  }
  __shared__ float sl[4], sc[4];
  if (lane == 0) { sl[w] = l; sc[w] = c; }
  __syncthreads();
  if (t == 0) {
    scalars[0] = (sl[0] + sl[1] + sl[2] + sl[3]) * (1.0f / (float)Bn);
    scalars[1] = (sc[0] + sc[1] + sc[2] + sc[3]) * (1.0f / (float)Bn);
  }
}

extern "C" void kernel_launch(void* const* d_in, const int* in_sizes, int n_in,
                              void* d_out, int out_size, void* d_ws, size_t ws_size,
                              hipStream_t stream) {
  const float* feats = (const float*)d_in[0];   // [H,B,D] fp32
  const float* W     = (const float*)d_in[1];   // [H,D,C] fp32
  const float* bias  = (const float*)d_in[2];   // [H,C]
  const int*   y     = (const int*)d_in[3];     // [B]
  float* out = (float*)d_out;                   // [B*C | B | 1 | 1]

  // ws: logits partials (49,152,000 B) + loss_b[512] + corr_b[512]
  float* logits = (float*)d_ws;
  float* loss_b = logits + (size_t)KSPLIT * Hn * Bn * Cn;
  float* corr_b = loss_b + Bn;
  float* out_exit    = out + (size_t)Bn * Cn;
  float* out_scalars = out + (size_t)Bn * Cn + Bn;

  gemm_k<<<dim3(Cpad / 128, Bn / 128, Hn * KSPLIT), 256, 0, stream>>>(
      feats, W, bias, logits);
  confpick_k<<<Bn, 256, 0, stream>>>(logits, y, out, out_exit, loss_b, corr_b);
  reduce_k<<<1, 256, 0, stream>>>(loss_b, corr_b, out_scalars);
}